// Round 1
// baseline (742.279 us; speedup 1.0000x reference)
//
#include <hip/hip_runtime.h>
#include <cstdint>
#include <cstddef>

constexpr int B = 8, C = 32, H = 512, W = 512;
constexpr int HW = H * W;

__device__ __forceinline__ float sigmoidf_(float z) {
    return 1.0f / (1.0f + __expf(-z));
}

// ---------------------------------------------------------------------------
// Kernel 1: patch gate + 1x1 conv (cat[product,x] @ conv_w) + channel max/mean
// grid (4 coltiles, 256 rowpairs, 8 batch), block 256
// Tile: 2 rows x 128 cols x 32 ch. LDS: xs 32KiB + gs 8KiB = 40KiB.
// ---------------------------------------------------------------------------
__global__ __launch_bounds__(256) void k1_gate_conv(
    const float* __restrict__ x, const float* __restrict__ mlp_w,
    const float* __restrict__ mlp_b, const float* __restrict__ conv_w,
    const float* __restrict__ conv_b, float* __restrict__ fs,
    float* __restrict__ cm, float* __restrict__ ca)
{
    __shared__ float xs[32][256];   // [c][row*128+col]
    __shared__ float gs[32][64];    // [c][patch_col]
    const int t  = threadIdx.x;
    const int c0 = blockIdx.x * 128;
    const int h0 = blockIdx.y * 2;
    const int b  = blockIdx.z;

    // phase 1: stage x tile (8192 floats) as float4, coalesced
    #pragma unroll
    for (int k = 0; k < 8; ++k) {
        int li = k * 256 + t;
        int c = li >> 6, q = li & 63;
        int p = q * 4;
        int row = p >> 7, col = p & 127;
        const float4 v = *(const float4*)(x + ((size_t)(b * C + c) * H + h0 + row) * W + c0 + col);
        *(float4*)&xs[c][p] = v;
    }
    __syncthreads();

    // phase 2: per-patch gates: sigmoid((max + mean) * w + 2b)
    const float gw = mlp_w[0];
    const float gb = 2.0f * mlp_b[0];
    #pragma unroll
    for (int k = 0; k < 8; ++k) {
        int gi = k * 256 + t;        // 32 ch * 64 patches = 2048
        int c = gi >> 6, wp = gi & 63;
        float a0 = xs[c][2 * wp],       a1 = xs[c][2 * wp + 1];
        float a2 = xs[c][128 + 2 * wp], a3 = xs[c][129 + 2 * wp];
        float mx = fmaxf(fmaxf(a0, a1), fmaxf(a2, a3));
        float av = 0.25f * ((a0 + a1) + (a2 + a3));
        gs[c][wp] = sigmoidf_(fmaf(mx + av, gw, gb));
    }
    __syncthreads();

    // phase 3: per-pixel 64->32 matvec; out[o] = sum_c xg*W1[o,c] + xv*W2[o,c]
    const int row = t >> 7, col = t & 127, wp = col >> 1;
    float xv[32], xg[32];
    #pragma unroll
    for (int c = 0; c < 32; ++c) {
        float v = xs[c][t];
        xv[c] = v;
        xg[c] = v * gs[c][wp];
    }
    float cmax = -3.4e38f, csum = 0.0f;
    const size_t pixoff = ((size_t)(b * C) * H + h0 + row) * W + c0 + col;
    #pragma unroll 4
    for (int o = 0; o < 32; ++o) {
        const float* wr = conv_w + o * 64;     // wave-uniform -> s_load
        float acc0 = conv_b[o], acc1 = 0.0f;   // two chains: ILP + <=1 SGPR/FMA
        #pragma unroll
        for (int c = 0; c < 32; ++c) {
            acc0 = fmaf(xg[c], wr[c],      acc0);
            acc1 = fmaf(xv[c], wr[32 + c], acc1);
        }
        float acc = acc0 + acc1;
        fs[pixoff + (size_t)o * HW] = acc;
        cmax = fmaxf(cmax, acc);
        csum += acc;
    }
    const size_t pp = ((size_t)b * H + h0 + row) * W + c0 + col;
    cm[pp] = cmax;
    ca[pp] = csum * (1.0f / 32.0f);
}

// ---------------------------------------------------------------------------
// Kernel 2: 7x7 conv (2ch -> 32ch, SAME) on [cm,ca], then out = sigmoid(att)*fs
// grid (2 coltiles, 128 rowtiles, 8 batch), block 256.
// Tile: 4 rows x 256 cols; thread = 1 row x 4 px; o in chunks of 8.
// LDS window: 2 x 10 x 264 floats = 20.6 KiB (halo 3, zero-padded).
// ---------------------------------------------------------------------------
__global__ __launch_bounds__(256) void k2_conv7_sigmul(
    const float* __restrict__ cm, const float* __restrict__ ca,
    const float* __restrict__ convout_w, const float* __restrict__ convout_b,
    float* __restrict__ io /* fs in, final out, in-place */)
{
    __shared__ float sm[2][10][264];
    const int t  = threadIdx.x;
    const int x0 = blockIdx.x * 256;
    const int y0 = blockIdx.y * 4;
    const int b  = blockIdx.z;

    // stage cm/ca window with zero padding
    for (int idx = t; idx < 2 * 10 * 264; idx += 256) {
        int j   = idx / (10 * 264);
        int rem = idx - j * (10 * 264);
        int r   = rem / 264;
        int cc  = rem - r * 264;
        int gy = y0 - 3 + r;
        int gx = x0 - 3 + cc;
        const float* P = j ? ca : cm;
        float v = 0.0f;
        if (cc < 262 && (unsigned)gy < (unsigned)H && (unsigned)gx < (unsigned)W)
            v = P[(size_t)b * HW + (size_t)gy * W + gx];
        sm[j][r][cc] = v;
    }
    __syncthreads();

    const int ty  = t >> 6;          // wave id = row within tile
    const int tx4 = (t & 63) * 4;    // 4 consecutive output cols per thread

    #pragma unroll 1
    for (int oc = 0; oc < 4; ++oc) {
        const int ob = oc * 8;
        float acc[8][4];
        #pragma unroll
        for (int o = 0; o < 8; ++o) {
            float bb = convout_b[ob + o];
            #pragma unroll
            for (int px = 0; px < 4; ++px) acc[o][px] = bb;
        }
        #pragma unroll 1
        for (int j = 0; j < 2; ++j) {
            #pragma unroll
            for (int dy = 0; dy < 7; ++dy) {
                const float* rp = &sm[j][ty + dy][tx4];  // 16B-aligned, contiguous
                float4 va = *(const float4*)&rp[0];
                float4 vb = *(const float4*)&rp[4];
                float2 vc = *(const float2*)&rp[8];
                float v[10] = {va.x, va.y, va.z, va.w,
                               vb.x, vb.y, vb.z, vb.w, vc.x, vc.y};
                #pragma unroll
                for (int dx = 0; dx < 7; ++dx) {
                    #pragma unroll
                    for (int o = 0; o < 8; ++o) {
                        // wave-uniform weight -> s_load; 1 SGPR per FMA
                        float wv = convout_w[((ob + o) * 2 + j) * 49 + dy * 7 + dx];
                        #pragma unroll
                        for (int px = 0; px < 4; ++px)
                            acc[o][px] = fmaf(v[dx + px], wv, acc[o][px]);
                    }
                }
            }
        }
        #pragma unroll
        for (int o = 0; o < 8; ++o) {
            const size_t base = ((size_t)(b * C + ob + o) * H + y0 + ty) * W + x0 + tx4;
            float4 f = *(const float4*)&io[base];
            float4 r;
            r.x = f.x * sigmoidf_(acc[o][0]);
            r.y = f.y * sigmoidf_(acc[o][1]);
            r.z = f.z * sigmoidf_(acc[o][2]);
            r.w = f.w * sigmoidf_(acc[o][3]);
            *(float4*)&io[base] = r;
        }
    }
}

extern "C" void kernel_launch(void* const* d_in, const int* in_sizes, int n_in,
                              void* d_out, int out_size, void* d_ws, size_t ws_size,
                              hipStream_t stream)
{
    const float* x         = (const float*)d_in[0];
    const float* mlp_w     = (const float*)d_in[1];
    const float* mlp_b     = (const float*)d_in[2];
    const float* conv_w    = (const float*)d_in[3];
    const float* conv_b    = (const float*)d_in[4];
    const float* convout_w = (const float*)d_in[5];
    const float* convout_b = (const float*)d_in[6];

    float* out = (float*)d_out;             // fs lives here between kernels
    float* cm  = (float*)d_ws;              // 8 MiB
    float* ca  = cm + (size_t)B * HW;       // 8 MiB (ws needs 16 MiB)

    k1_gate_conv<<<dim3(4, 256, 8), 256, 0, stream>>>(
        x, mlp_w, mlp_b, conv_w, conv_b, out, cm, ca);
    k2_conv7_sigmul<<<dim3(2, 128, 8), 256, 0, stream>>>(
        cm, ca, convout_w, convout_b, out);
}

// Round 2
// 680.942 us; speedup vs baseline: 1.0901x; 1.0901x over previous
//
#include <hip/hip_runtime.h>
#include <cstdint>
#include <cstddef>

constexpr int B = 8, C = 32, H = 512, W = 512;
constexpr int HW = H * W;

__device__ __forceinline__ float sigmoidf_(float z) {
    return 1.0f / (1.0f + __expf(-z));
}

// ---------------------------------------------------------------------------
// Kernel 1: patch gate + 1x1 conv (cat[product,x] @ conv_w) + channel max/mean
// grid (4 coltiles, 256 rowpairs, 8 batch), block 256
// Tile: 2 rows x 128 cols x 32 ch. LDS: xs 32KiB + gs 8KiB = 40KiB.
// __launch_bounds__(256,4): 4 waves/EU -> VGPR budget 128, so xv/xg stay in
// registers (round 1: VGPR=56 forced LDS rematerialization of both arrays,
// ~2048 extra ds_read_b32/thread -> LDS-issue-bound at 269us).
// LDS caps at 4 blocks/CU (160/40) = 16 waves/CU anyway, so no occupancy loss.
// ---------------------------------------------------------------------------
__global__ __launch_bounds__(256, 4) void k1_gate_conv(
    const float* __restrict__ x, const float* __restrict__ mlp_w,
    const float* __restrict__ mlp_b, const float* __restrict__ conv_w,
    const float* __restrict__ conv_b, float* __restrict__ fs,
    float* __restrict__ cm, float* __restrict__ ca)
{
    __shared__ float xs[32][256];   // [c][row*128+col]
    __shared__ float gs[32][64];    // [c][patch_col]
    const int t  = threadIdx.x;
    const int c0 = blockIdx.x * 128;
    const int h0 = blockIdx.y * 2;
    const int b  = blockIdx.z;

    // phase 1: stage x tile (8192 floats) as float4, coalesced
    #pragma unroll
    for (int k = 0; k < 8; ++k) {
        int li = k * 256 + t;
        int c = li >> 6, q = li & 63;
        int p = q * 4;
        int row = p >> 7, col = p & 127;
        const float4 v = *(const float4*)(x + ((size_t)(b * C + c) * H + h0 + row) * W + c0 + col);
        *(float4*)&xs[c][p] = v;
    }
    __syncthreads();

    // phase 2: per-patch gates: sigmoid((max + mean) * w + 2b)
    const float gw = mlp_w[0];
    const float gb = 2.0f * mlp_b[0];
    #pragma unroll
    for (int k = 0; k < 8; ++k) {
        int gi = k * 256 + t;        // 32 ch * 64 patches = 2048
        int c = gi >> 6, wp = gi & 63;
        float a0 = xs[c][2 * wp],       a1 = xs[c][2 * wp + 1];
        float a2 = xs[c][128 + 2 * wp], a3 = xs[c][129 + 2 * wp];
        float mx = fmaxf(fmaxf(a0, a1), fmaxf(a2, a3));
        float av = 0.25f * ((a0 + a1) + (a2 + a3));
        gs[c][wp] = sigmoidf_(fmaf(mx + av, gw, gb));
    }
    __syncthreads();

    // phase 3: per-pixel 64->32 matvec; out[o] = sum_c xg*W1[o,c] + xv*W2[o,c]
    const int row = t >> 7, col = t & 127, wp = col >> 1;
    float xv[32], xg[32];
    #pragma unroll
    for (int c = 0; c < 32; ++c) {
        float v = xs[c][t];
        xv[c] = v;
        xg[c] = v * gs[c][wp];
    }
    float cmax = -3.4e38f, csum = 0.0f;
    const size_t pixoff = ((size_t)(b * C) * H + h0 + row) * W + c0 + col;
    #pragma unroll 4
    for (int o = 0; o < 32; ++o) {
        const float* wr = conv_w + o * 64;     // wave-uniform -> s_load
        float acc0 = conv_b[o], acc1 = 0.0f;   // two chains: ILP + <=1 SGPR/FMA
        #pragma unroll
        for (int c = 0; c < 32; ++c) {
            acc0 = fmaf(xg[c], wr[c],      acc0);
            acc1 = fmaf(xv[c], wr[32 + c], acc1);
        }
        float acc = acc0 + acc1;
        fs[pixoff + (size_t)o * HW] = acc;
        cmax = fmaxf(cmax, acc);
        csum += acc;
    }
    const size_t pp = ((size_t)b * H + h0 + row) * W + c0 + col;
    cm[pp] = cmax;
    ca[pp] = csum * (1.0f / 32.0f);
}

// ---------------------------------------------------------------------------
// Kernel 2: 7x7 conv (2ch -> 32ch, SAME) on [cm,ca], then out = sigmoid(att)*fs
// grid (2 coltiles, 128 rowtiles, 8 batch), block 256.
// Tile: 4 rows x 256 cols; thread = 1 row x 4 px; o in chunks of 8.
// LDS window: 2 x 10 x 264 floats = 20.6 KiB (halo 3, zero-padded).
// __launch_bounds__(256,4): same VGPR-budget reasoning as k1 (acc[8][4]=32
// + v[10] + addressing must stay in registers).
// ---------------------------------------------------------------------------
__global__ __launch_bounds__(256, 4) void k2_conv7_sigmul(
    const float* __restrict__ cm, const float* __restrict__ ca,
    const float* __restrict__ convout_w, const float* __restrict__ convout_b,
    float* __restrict__ io /* fs in, final out, in-place */)
{
    __shared__ float sm[2][10][264];
    const int t  = threadIdx.x;
    const int x0 = blockIdx.x * 256;
    const int y0 = blockIdx.y * 4;
    const int b  = blockIdx.z;

    // stage cm/ca window with zero padding
    for (int idx = t; idx < 2 * 10 * 264; idx += 256) {
        int j   = idx / (10 * 264);
        int rem = idx - j * (10 * 264);
        int r   = rem / 264;
        int cc  = rem - r * 264;
        int gy = y0 - 3 + r;
        int gx = x0 - 3 + cc;
        const float* P = j ? ca : cm;
        float v = 0.0f;
        if (cc < 262 && (unsigned)gy < (unsigned)H && (unsigned)gx < (unsigned)W)
            v = P[(size_t)b * HW + (size_t)gy * W + gx];
        sm[j][r][cc] = v;
    }
    __syncthreads();

    const int ty  = t >> 6;          // wave id = row within tile
    const int tx4 = (t & 63) * 4;    // 4 consecutive output cols per thread

    #pragma unroll 1
    for (int oc = 0; oc < 4; ++oc) {
        const int ob = oc * 8;
        float acc[8][4];
        #pragma unroll
        for (int o = 0; o < 8; ++o) {
            float bb = convout_b[ob + o];
            #pragma unroll
            for (int px = 0; px < 4; ++px) acc[o][px] = bb;
        }
        #pragma unroll 1
        for (int j = 0; j < 2; ++j) {
            #pragma unroll
            for (int dy = 0; dy < 7; ++dy) {
                const float* rp = &sm[j][ty + dy][tx4];  // 16B-aligned, contiguous
                float4 va = *(const float4*)&rp[0];
                float4 vb = *(const float4*)&rp[4];
                float2 vc = *(const float2*)&rp[8];
                float v[10] = {va.x, va.y, va.z, va.w,
                               vb.x, vb.y, vb.z, vb.w, vc.x, vc.y};
                #pragma unroll
                for (int dx = 0; dx < 7; ++dx) {
                    #pragma unroll
                    for (int o = 0; o < 8; ++o) {
                        // wave-uniform weight -> s_load; 1 SGPR per FMA
                        float wv = convout_w[((ob + o) * 2 + j) * 49 + dy * 7 + dx];
                        #pragma unroll
                        for (int px = 0; px < 4; ++px)
                            acc[o][px] = fmaf(v[dx + px], wv, acc[o][px]);
                    }
                }
            }
        }
        #pragma unroll
        for (int o = 0; o < 8; ++o) {
            const size_t base = ((size_t)(b * C + ob + o) * H + y0 + ty) * W + x0 + tx4;
            float4 f = *(const float4*)&io[base];
            float4 r;
            r.x = f.x * sigmoidf_(acc[o][0]);
            r.y = f.y * sigmoidf_(acc[o][1]);
            r.z = f.z * sigmoidf_(acc[o][2]);
            r.w = f.w * sigmoidf_(acc[o][3]);
            *(float4*)&io[base] = r;
        }
    }
}

extern "C" void kernel_launch(void* const* d_in, const int* in_sizes, int n_in,
                              void* d_out, int out_size, void* d_ws, size_t ws_size,
                              hipStream_t stream)
{
    const float* x         = (const float*)d_in[0];
    const float* mlp_w     = (const float*)d_in[1];
    const float* mlp_b     = (const float*)d_in[2];
    const float* conv_w    = (const float*)d_in[3];
    const float* conv_b    = (const float*)d_in[4];
    const float* convout_w = (const float*)d_in[5];
    const float* convout_b = (const float*)d_in[6];

    float* out = (float*)d_out;             // fs lives here between kernels
    float* cm  = (float*)d_ws;              // 8 MiB
    float* ca  = cm + (size_t)B * HW;       // 8 MiB (ws needs 16 MiB)

    k1_gate_conv<<<dim3(4, 256, 8), 256, 0, stream>>>(
        x, mlp_w, mlp_b, conv_w, conv_b, out, cm, ca);
    k2_conv7_sigmul<<<dim3(2, 128, 8), 256, 0, stream>>>(
        cm, ca, convout_w, convout_b, out);
}